// Round 10
// baseline (286.341 us; speedup 1.0000x reference)
//
#include <hip/hip_runtime.h>
#include <hip/hip_fp16.h>

// WHTConv2D fused: out = Rw(Rh(g(Rh(Rw(x))))) + x ; Rw/Rh = normalized FWHT-256.
// x: (8,64,256,256) f32 -> 512 planes. One 1024-thread block per plane, plane
// staged in LDS fp16, pitch 264 halves (132 dwords -> 4-bank row stagger).
// v,T pre-packed (v,|T|) fp16 in d_ws by k_prep.
//
// Round-10: same 7-pass radix-16 structure as round-9, but with a SPLIT w-layout
// inside each LDS row: w=16s+j stored at halves 8s+j (j<8) / 128+8s+(j-8) (j>=8).
// Round-9's b128 passes had lanes at stride-8 dwords -> 8-way bank conflicts
// (2.62M/dispatch). With the split layout every pass is lane-contiguous or
// 2-lanes/bank (the empirically-free patterns of rounds 6-8):
//   P1/P7: uint4 at dword 132r+4s (+64) -> 64 contiguous dwords per 16-lane phase
//   P2/P6: banks = 4row + (wk2&3) -> exactly 2 lanes/bank
//   P3/P4/P5: row-uniform per instruction (unchanged)
// P4 maps LDS column c -> true w for the v/T lookup.

#define NPX   65536   // pixels per plane (global pitch 256)
#define PITCH 264     // LDS halves per row
#define SC    0.0625f // 1/sqrt(256)

__device__ __forceinline__ unsigned int h2u(__half2 h) {
  union { __half2 h; unsigned int u; } c; c.h = h; return c.u;
}
__device__ __forceinline__ __half2 u2h(unsigned int u) {
  union { __half2 h; unsigned int u; } c; c.u = u; return c.h;
}

// 16-point unnormalized FWHT fully in registers.
__device__ __forceinline__ void fwht16(float f[16]) {
  #pragma unroll
  for (int d = 1; d < 16; d <<= 1) {
    #pragma unroll
    for (int i = 0; i < 16; ++i) {
      if (!(i & d)) {
        float a = f[i], b = f[i | d];
        f[i]     = a + b;
        f[i | d] = a - b;
      }
    }
  }
}

// g term with signed tanh: tanh(a)*relu(|a|-absT)
__device__ __forceinline__ float g_term(float a, float absT) {
  float e  = __builtin_amdgcn_exp2f(a * 2.8853900817779268f);  // exp(2a)
  float th = 1.0f - 2.0f * __builtin_amdgcn_rcpf(e + 1.0f);    // tanh(a)
  float rl = fmaxf(fabsf(a) - absT, 0.0f);
  return th * rl;
}

// ---- prep: W[p][pix] = half2(v, |T|) packed in one u32 ----
__global__ __launch_bounds__(256) void k_prep(const float* __restrict__ v,
                                              const float* __restrict__ T,
                                              unsigned int* __restrict__ W) {
  const int i = 4 * (blockIdx.x * 256 + threadIdx.x);
  const float4 v4 = *reinterpret_cast<const float4*>(v + i);
  const float4 t4 = *reinterpret_cast<const float4*>(T + i);
  uint4 w;
  w.x = h2u(__floats2half2_rn(v4.x, fabsf(t4.x)));
  w.y = h2u(__floats2half2_rn(v4.y, fabsf(t4.y)));
  w.z = h2u(__floats2half2_rn(v4.z, fabsf(t4.z)));
  w.w = h2u(__floats2half2_rn(v4.w, fabsf(t4.w)));
  *reinterpret_cast<uint4*>(W + i) = w;
}

__global__ __launch_bounds__(1024) void k_fused(const float* __restrict__ x,
                                                const unsigned int* __restrict__ W,
                                                float* __restrict__ out) {
  __shared__ __align__(16) __half S[256 * PITCH];   // 132 KiB
  const int tid = threadIdx.x;
  const size_t pbase = (size_t)blockIdx.x * NPX;

  // ---- P1: load x (16 contig w), fwht16 over w_lo, split-store fp16 ----
  #pragma unroll 1
  for (int it = 0; it < 4; ++it) {
    const int task = it * 1024 + tid;
    const int row = task >> 4, seg = task & 15;
    const float* xp = x + pbase + (size_t)row * 256 + seg * 16;
    float f[16];
    #pragma unroll
    for (int j = 0; j < 4; ++j) {
      const float4 t4 = *reinterpret_cast<const float4*>(xp + 4 * j);
      f[4*j] = t4.x; f[4*j+1] = t4.y; f[4*j+2] = t4.z; f[4*j+3] = t4.w;
    }
    fwht16(f);
    __half* sp = &S[row * PITCH];
    uint4 w0, w1;
    w0.x = h2u(__floats2half2_rn(f[0],  f[1]));
    w0.y = h2u(__floats2half2_rn(f[2],  f[3]));
    w0.z = h2u(__floats2half2_rn(f[4],  f[5]));
    w0.w = h2u(__floats2half2_rn(f[6],  f[7]));
    w1.x = h2u(__floats2half2_rn(f[8],  f[9]));
    w1.y = h2u(__floats2half2_rn(f[10], f[11]));
    w1.z = h2u(__floats2half2_rn(f[12], f[13]));
    w1.w = h2u(__floats2half2_rn(f[14], f[15]));
    *reinterpret_cast<uint4*>(sp + 8 * seg)       = w0;   // j=0..7
    *reinterpret_cast<uint4*>(sp + 128 + 8 * seg) = w1;   // j=8..15
  }
  __syncthreads();

  // ---- P2: fwht16 over w_hi, scale SC (forward Rw complete) ----
  // slot wk2 0..7 -> base dword row*132 + (wk2>>2)*64 + (wk2&3); stride 4 dw.
  #pragma unroll 1
  for (int it = 0; it < 2; ++it) {
    const int task = it * 1024 + tid;
    const int wk2 = task & 7;
    const int row = task >> 3;
    unsigned int* sp = reinterpret_cast<unsigned int*>(&S[row * PITCH]) +
                       ((wk2 >> 2) * 64 + (wk2 & 3));
    float fA[16], fB[16];
    #pragma unroll
    for (int a = 0; a < 16; ++a) {
      const float2 e = __half22float2(u2h(sp[4 * a]));
      fA[a] = e.x; fB[a] = e.y;
    }
    fwht16(fA); fwht16(fB);
    #pragma unroll
    for (int a = 0; a < 16; ++a)
      sp[4 * a] = h2u(__floats2half2_rn(fA[a] * SC, fB[a] * SC));
  }
  __syncthreads();

  // ---- P3: fwht16 over h_lo (rows 16g+k), no scale ----
  const int q = tid & 63;       // wave-uniform g => wave-uniform row per instr
  const int g = tid >> 6;
  #pragma unroll 1
  for (int hs = 0; hs < 2; ++hs) {
    const int cb = 2 * q + 128 * hs;
    float fA[16], fB[16];
    #pragma unroll
    for (int k = 0; k < 16; ++k) {
      const float2 e = __half22float2(
          u2h(*reinterpret_cast<unsigned int*>(&S[(16 * g + k) * PITCH + cb])));
      fA[k] = e.x; fB[k] = e.y;
    }
    fwht16(fA); fwht16(fB);
    #pragma unroll
    for (int k = 0; k < 16; ++k)
      *reinterpret_cast<unsigned int*>(&S[(16 * g + k) * PITCH + cb]) =
          h2u(__floats2half2_rn(fA[k], fB[k]));
  }
  __syncthreads();

  // ---- P4: fwht16 over h_hi -> xSC (f2 done) -> g -> fwht16 over h_hi -> xSC ----
  {
    const int c   = tid & 255;                // LDS half-column
    const int grp = tid >> 8;
    // true w for this LDS column (split layout inverse)
    const int w_true = (((c & 127) >> 3) << 4) + ((c >> 7) << 3) + (c & 7);
    float f[16];
    #pragma unroll 1
    for (int gg = grp; gg < 16; gg += 4) {
      #pragma unroll
      for (int a = 0; a < 16; ++a)
        f[a] = __half2float(S[(gg + 16 * a) * PITCH + c]);
      fwht16(f);
      #pragma unroll
      for (int a = 0; a < 16; ++a) f[a] *= SC;

      #pragma unroll 4
      for (int a = 0; a < 16; ++a) {
        const int off = (gg + 16 * a) * 256 + w_true;   // global pitch 256
        float acc = 0.f;
        #pragma unroll
        for (int p = 0; p < 4; ++p) {
          const float2 w = __half22float2(u2h(W[p * NPX + off]));  // (v, |T|)
          acc += g_term(f[a] * w.x, w.y);
        }
        f[a] = acc;
      }

      fwht16(f);
      #pragma unroll
      for (int a = 0; a < 16; ++a)
        S[(gg + 16 * a) * PITCH + c] = __float2half_rn(f[a] * SC);
    }
  }
  __syncthreads();

  // ---- P5: fwht16 over h_lo (inverse), no scale ----
  #pragma unroll 1
  for (int hs = 0; hs < 2; ++hs) {
    const int cb = 2 * q + 128 * hs;
    float fA[16], fB[16];
    #pragma unroll
    for (int k = 0; k < 16; ++k) {
      const float2 e = __half22float2(
          u2h(*reinterpret_cast<unsigned int*>(&S[(16 * g + k) * PITCH + cb])));
      fA[k] = e.x; fB[k] = e.y;
    }
    fwht16(fA); fwht16(fB);
    #pragma unroll
    for (int k = 0; k < 16; ++k)
      *reinterpret_cast<unsigned int*>(&S[(16 * g + k) * PITCH + cb]) =
          h2u(__floats2half2_rn(fA[k], fB[k]));
  }
  __syncthreads();

  // ---- P6: fwht16 over w_hi (inverse), no scale (SC folded into P7 fma) ----
  #pragma unroll 1
  for (int it = 0; it < 2; ++it) {
    const int task = it * 1024 + tid;
    const int wk2 = task & 7;
    const int row = task >> 3;
    unsigned int* sp = reinterpret_cast<unsigned int*>(&S[row * PITCH]) +
                       ((wk2 >> 2) * 64 + (wk2 & 3));
    float fA[16], fB[16];
    #pragma unroll
    for (int a = 0; a < 16; ++a) {
      const float2 e = __half22float2(u2h(sp[4 * a]));
      fA[a] = e.x; fB[a] = e.y;
    }
    fwht16(fA); fwht16(fB);
    #pragma unroll
    for (int a = 0; a < 16; ++a)
      sp[4 * a] = h2u(__floats2half2_rn(fA[a], fB[a]));
  }
  __syncthreads();

  // ---- P7: fwht16 over w_lo (inverse) * SC + x residual -> out ----
  #pragma unroll 1
  for (int it = 0; it < 4; ++it) {
    const int task = it * 1024 + tid;
    const int row = task >> 4, seg = task & 15;
    const __half* sp = &S[row * PITCH];
    const uint4 w0 = *reinterpret_cast<const uint4*>(sp + 8 * seg);
    const uint4 w1 = *reinterpret_cast<const uint4*>(sp + 128 + 8 * seg);
    float f[16];
    { float2 e;
      e = __half22float2(u2h(w0.x)); f[0]  = e.x; f[1]  = e.y;
      e = __half22float2(u2h(w0.y)); f[2]  = e.x; f[3]  = e.y;
      e = __half22float2(u2h(w0.z)); f[4]  = e.x; f[5]  = e.y;
      e = __half22float2(u2h(w0.w)); f[6]  = e.x; f[7]  = e.y;
      e = __half22float2(u2h(w1.x)); f[8]  = e.x; f[9]  = e.y;
      e = __half22float2(u2h(w1.y)); f[10] = e.x; f[11] = e.y;
      e = __half22float2(u2h(w1.z)); f[12] = e.x; f[13] = e.y;
      e = __half22float2(u2h(w1.w)); f[14] = e.x; f[15] = e.y;
    }
    fwht16(f);
    const float* xp = x + pbase + (size_t)row * 256 + seg * 16;
    float* op = out + pbase + (size_t)row * 256 + seg * 16;
    #pragma unroll
    for (int j = 0; j < 4; ++j) {
      const float4 xv = *reinterpret_cast<const float4*>(xp + 4 * j);
      float4 o;
      o.x = fmaf(f[4*j],     SC, xv.x);
      o.y = fmaf(f[4*j + 1], SC, xv.y);
      o.z = fmaf(f[4*j + 2], SC, xv.z);
      o.w = fmaf(f[4*j + 3], SC, xv.w);
      *reinterpret_cast<float4*>(op + 4 * j) = o;
    }
  }
}

extern "C" void kernel_launch(void* const* d_in, const int* in_sizes, int n_in,
                              void* d_out, int out_size, void* d_ws, size_t ws_size,
                              hipStream_t stream) {
  const float* x = (const float*)d_in[0];
  const float* v = (const float*)d_in[1];
  const float* T = (const float*)d_in[2];
  float* out = (float*)d_out;
  unsigned int* W = (unsigned int*)d_ws;   // 1 MB packed (v,|T|) fp16

  k_prep<<<256, 256, 0, stream>>>(v, T, W);
  k_fused<<<512, 1024, 0, stream>>>(x, W, out);
}

// Round 11
// 168.747 us; speedup vs baseline: 1.6969x; 1.6969x over previous
//
#include <hip/hip_runtime.h>
#include <hip/hip_fp16.h>

// WHTConv2D fused single-kernel: out = Rw(Rh(g(Rh(Rw(x))))) + x
//   Rw/Rh = normalized FWHT-256 along w/h (separable; order swapped vs ref, exact)
//   g(f)[h,w] = sum_p tanh(f*v_p) * relu(|f*v_p| - |T_p|)
// x: (8,64,256,256) f32 -> 512 planes. One 1024-thread block per plane, plane
// staged in LDS fp16 (128 KB static, pitch 256). v,T pre-packed (v,|T|) fp16.
//
// Round-11: REVERT to round-8 structure (7-pass b128 rounds 9/10 regressed:
// bank model wrong twice, 2.4M conflicts). Single change vs round-8: remove
// the two SAME-WAVE barriers.
//   phase1 -> passA: wave g reads rows 16g..16g+15 = rows wave g itself wrote
//   passC -> phase3: wave wv reads rows 16wv..16wv+15 = rows it wrote (g==wv)
// DS ops are in-order per wave and the compiler preserves ds_write->ds_read
// order on S[], so no barrier is needed; waves pipeline through the phase
// boundary instead of convergence-stalling. Cross-wave barriers A->B, B->C stay.

#define NPX 65536   // pixels per plane
#define SC  0.0625f // 1/sqrt(256)

__device__ __forceinline__ unsigned int h2u(__half2 h) {
  union { __half2 h; unsigned int u; } c; c.h = h; return c.u;
}
__device__ __forceinline__ __half2 u2h(unsigned int u) {
  union { __half2 h; unsigned int u; } c; c.u = u; return c.h;
}

// 16-point unnormalized FWHT fully in registers.
__device__ __forceinline__ void fwht16(float f[16]) {
  #pragma unroll
  for (int d = 1; d < 16; d <<= 1) {
    #pragma unroll
    for (int i = 0; i < 16; ++i) {
      if (!(i & d)) {
        float a = f[i], b = f[i | d];
        f[i]     = a + b;
        f[i | d] = a - b;
      }
    }
  }
}

// 256-point unnormalized FWHT across one wave; lane holds elems i = 4*lane + j.
__device__ __forceinline__ void fwht256_wave(float r[4], int lane) {
  float a0 = r[0] + r[1], b0 = r[0] - r[1];
  float a1 = r[2] + r[3], b1 = r[2] - r[3];
  r[0] = a0 + a1; r[1] = b0 + b1; r[2] = a0 - a1; r[3] = b0 - b1;
  #pragma unroll
  for (int m = 1; m <= 32; m <<= 1) {
    const float s = (lane & m) ? -1.0f : 1.0f;
    #pragma unroll
    for (int j = 0; j < 4; ++j) {
      float t = __shfl_xor(r[j], m);
      r[j] = fmaf(r[j], s, t);   // low lane: r+t ; high lane: t-r
    }
  }
}

// g term with signed tanh: tanh(a)*relu(|a|-absT)
__device__ __forceinline__ float g_term(float a, float absT) {
  float e  = __builtin_amdgcn_exp2f(a * 2.8853900817779268f);  // exp(2a)
  float th = 1.0f - 2.0f * __builtin_amdgcn_rcpf(e + 1.0f);    // tanh(a)
  float rl = fmaxf(fabsf(a) - absT, 0.0f);                     // fabs = src mod
  return th * rl;
}

// ---- prep: W[p][pix] = half2(v, |T|) packed in one u32 ----
__global__ __launch_bounds__(256) void k_prep(const float* __restrict__ v,
                                              const float* __restrict__ T,
                                              unsigned int* __restrict__ W) {
  const int i = 4 * (blockIdx.x * 256 + threadIdx.x);
  const float4 v4 = *reinterpret_cast<const float4*>(v + i);
  const float4 t4 = *reinterpret_cast<const float4*>(T + i);
  uint4 w;
  w.x = h2u(__floats2half2_rn(v4.x, fabsf(t4.x)));
  w.y = h2u(__floats2half2_rn(v4.y, fabsf(t4.y)));
  w.z = h2u(__floats2half2_rn(v4.z, fabsf(t4.z)));
  w.w = h2u(__floats2half2_rn(v4.w, fabsf(t4.w)));
  *reinterpret_cast<uint4*>(W + i) = w;
}

__global__ __launch_bounds__(1024) void k_fused(const float* __restrict__ x,
                                                const unsigned int* __restrict__ W,
                                                float* __restrict__ out) {
  __shared__ __half S[256 * 256];          // 128 KiB static, pitch 256
  const int tid  = threadIdx.x;
  const int lane = tid & 63;
  const int wv   = tid >> 6;               // wave id 0..15
  const size_t pbase = (size_t)blockIdx.x * NPX;

  // ---- phase 1: row FWHT of x -> LDS (fp16, x SC) ----
  #pragma unroll 2
  for (int rr = 0; rr < 16; ++rr) {
    const int row = wv * 16 + rr;
    const float4 xv = *reinterpret_cast<const float4*>(x + pbase + (size_t)row * 256 + 4 * lane);
    float r[4] = {xv.x, xv.y, xv.z, xv.w};
    fwht256_wave(r, lane);
    uint2 pk;
    pk.x = h2u(__floats2half2_rn(r[0] * SC, r[1] * SC));
    pk.y = h2u(__floats2half2_rn(r[2] * SC, r[3] * SC));
    *reinterpret_cast<uint2*>(&S[row * 256 + 4 * lane]) = pk;
  }
  // NO barrier: pass A (wave g) reads only rows 16g..16g+15 = this wave's writes.

  // ---- phase 2: column Rh o g o Rh, radix-16 (h = 16a + k) ----
  const int q = tid & 63;                  // for passes A/C (column pairs)
  const int g = tid >> 6;                  // wave-uniform row group, passes A/C
  const int c   = tid & 255;               // for pass B (single column)
  const int grp = tid >> 8;                // 0..3, pass B g-subset
  float fp[2][16];

  // pass A: FWHT16 over k (contiguous rows 16g+k); two half-sweeps, b32 LDS
  #pragma unroll 1
  for (int hs = 0; hs < 2; ++hs) {
    const int cb = 2 * q + 128 * hs;
    #pragma unroll
    for (int k = 0; k < 16; ++k) {
      unsigned int d = *reinterpret_cast<unsigned int*>(&S[(16 * g + k) * 256 + cb]);
      float2 e = __half22float2(u2h(d));
      fp[0][k] = e.x; fp[1][k] = e.y;
    }
    fwht16(fp[0]); fwht16(fp[1]);
    #pragma unroll
    for (int k = 0; k < 16; ++k) {
      *reinterpret_cast<unsigned int*>(&S[(16 * g + k) * 256 + cb]) =
          h2u(__floats2half2_rn(fp[0][k], fp[1][k]));
    }
  }
  __syncthreads();   // cross-wave: pass B reads all row groups

  // pass B: rows gg+16a: FWHT16 over a (completes Rh1) -> xSC -> g -> FWHT16
  // over a (first half of Rh2) -> xSC -> back to LDS.
  // Four quarter-sweeps of ONE column: f[16] live, packed (v,|T|) u32 loads.
  {
    float f[16];
    #pragma unroll 1
    for (int gg = grp; gg < 16; gg += 4) {
      #pragma unroll
      for (int a = 0; a < 16; ++a)
        f[a] = __half2float(S[(gg + 16 * a) * 256 + c]);
      fwht16(f);
      #pragma unroll
      for (int a = 0; a < 16; ++a) f[a] *= SC;

      #pragma unroll 4
      for (int a = 0; a < 16; ++a) {
        const int off = (gg + 16 * a) * 256 + c;
        float acc = 0.f;
        #pragma unroll
        for (int p = 0; p < 4; ++p) {
          const float2 w = __half22float2(u2h(W[p * NPX + off]));  // (v, |T|)
          acc += g_term(f[a] * w.x, w.y);
        }
        f[a] = acc;
      }

      fwht16(f);
      #pragma unroll
      for (int a = 0; a < 16; ++a)
        S[(gg + 16 * a) * 256 + c] = __float2half_rn(f[a] * SC);
    }
  }
  __syncthreads();   // cross-wave: pass C reads all row groups

  // pass C: FWHT16 over k (second half of Rh2; scale already applied)
  #pragma unroll 1
  for (int hs = 0; hs < 2; ++hs) {
    const int cb = 2 * q + 128 * hs;
    #pragma unroll
    for (int k = 0; k < 16; ++k) {
      unsigned int d = *reinterpret_cast<unsigned int*>(&S[(16 * g + k) * 256 + cb]);
      float2 e = __half22float2(u2h(d));
      fp[0][k] = e.x; fp[1][k] = e.y;
    }
    fwht16(fp[0]); fwht16(fp[1]);
    #pragma unroll
    for (int k = 0; k < 16; ++k) {
      *reinterpret_cast<unsigned int*>(&S[(16 * g + k) * 256 + cb]) =
          h2u(__floats2half2_rn(fp[0][k], fp[1][k]));
    }
  }
  // NO barrier: phase 3 (wave wv) reads only rows 16wv..16wv+15 = rows
  // written by pass C threads with g == wv (same wave).

  // ---- phase 3: row FWHT (x SC) + x residual -> out ----
  #pragma unroll 2
  for (int rr = 0; rr < 16; ++rr) {
    const int row = wv * 16 + rr;
    uint2 pk = *reinterpret_cast<uint2*>(&S[row * 256 + 4 * lane]);
    float2 lo = __half22float2(u2h(pk.x));
    float2 hi = __half22float2(u2h(pk.y));
    float r[4] = {lo.x, lo.y, hi.x, hi.y};
    fwht256_wave(r, lane);
    const float4 xv = *reinterpret_cast<const float4*>(x + pbase + (size_t)row * 256 + 4 * lane);
    float4 o;
    o.x = fmaf(r[0], SC, xv.x);
    o.y = fmaf(r[1], SC, xv.y);
    o.z = fmaf(r[2], SC, xv.z);
    o.w = fmaf(r[3], SC, xv.w);
    *reinterpret_cast<float4*>(out + pbase + (size_t)row * 256 + 4 * lane) = o;
  }
}

extern "C" void kernel_launch(void* const* d_in, const int* in_sizes, int n_in,
                              void* d_out, int out_size, void* d_ws, size_t ws_size,
                              hipStream_t stream) {
  const float* x = (const float*)d_in[0];
  const float* v = (const float*)d_in[1];
  const float* T = (const float*)d_in[2];
  float* out = (float*)d_out;
  unsigned int* W = (unsigned int*)d_ws;   // 1 MB packed (v,|T|) fp16

  k_prep<<<256, 256, 0, stream>>>(v, T, W);
  k_fused<<<512, 1024, 0, stream>>>(x, W, out);
}